// Round 1
// baseline (523.822 us; speedup 1.0000x reference)
//
#include <hip/hip_runtime.h>
#include <cstdint>

#define HW  128
#define NCH 256
#define NOC 18      // G*K*K = 2*9
#define EPSBN 1e-5f

// ---------------- Kernel A: conv(3x3, reflect) + BN(eval) + softmax(18) ----
// grid: 1024 blocks (one per (n,y) row), 128 threads (one per pixel x)
__global__ __launch_bounds__(128) void pasa_conv_softmax(
    const float* __restrict__ x, const float* __restrict__ w,
    const float* __restrict__ gamma, const float* __restrict__ beta,
    const float* __restrict__ rmean, const float* __restrict__ rvar,
    float* __restrict__ sigma)
{
    // XCD swizzle: each of the 8 XCDs gets one image, y-contiguous.
    int flat = blockIdx.x;            // [0,1024)
    int nf   = (flat & 7) * 128 + (flat >> 3);
    const int n = nf >> 7;            // [0,8)
    const int y = nf & 127;           // [0,128)

    const int px = threadIdx.x;       // [0,128)

    const int ym = (y == 0)      ? 1        : y - 1;   // reflect rows
    const int yp = (y == HW - 1) ? HW - 2   : y + 1;
    const int xm = (px == 0)       ? 1      : px - 1;  // reflect cols
    const int xq = (px == HW - 1)  ? HW - 2 : px + 1;

    const float* xn = x + (size_t)n * NCH * HW * HW;

    float acc[NOC];
    #pragma unroll
    for (int i = 0; i < NOC; ++i) acc[i] = 0.0f;

    for (int ic = 0; ic < NCH; ++ic) {
        const float* xc = xn + (size_t)ic * (HW * HW);
        const float* r0 = xc + ym * HW;
        const float* r1 = xc + y  * HW;
        const float* r2 = xc + yp * HW;
        float v[9];
        v[0] = r0[xm]; v[1] = r0[px]; v[2] = r0[xq];
        v[3] = r1[xm]; v[4] = r1[px]; v[5] = r1[xq];
        v[6] = r2[xm]; v[7] = r2[px]; v[8] = r2[xq];

        const float* wic = w + ic * 9;   // w[oc][ic][k], oc stride = NCH*9
        #pragma unroll
        for (int oc = 0; oc < NOC; ++oc) {
            const float* wo = wic + oc * (NCH * 9);  // wave-uniform address -> s_load
            #pragma unroll
            for (int k = 0; k < 9; ++k)
                acc[oc] = fmaf(v[k], wo[k], acc[oc]);
        }
    }

    // BN (eval) + softmax over the 18 channels
    float vals[NOC];
    float m = -1e30f;
    #pragma unroll
    for (int oc = 0; oc < NOC; ++oc) {
        float sc = gamma[oc] * rsqrtf(rvar[oc] + EPSBN);
        float b  = beta[oc] - rmean[oc] * sc;
        float t  = fmaf(acc[oc], sc, b);
        vals[oc] = t;
        m = fmaxf(m, t);
    }
    float s = 0.0f;
    #pragma unroll
    for (int oc = 0; oc < NOC; ++oc) { vals[oc] = __expf(vals[oc] - m); s += vals[oc]; }
    const float inv = 1.0f / s;

    float* so = sigma + (size_t)n * NOC * HW * HW + (size_t)y * HW + px;
    #pragma unroll
    for (int oc = 0; oc < NOC; ++oc)
        so[(size_t)oc * HW * HW] = vals[oc] * inv;
}

// ---------------- Kernel B: per-pixel dynamic 3x3 pooling ------------------
// grid: 512 blocks; block 256 threads: q=tid&31 (pixel quad), r=(tid>>5)&3
// (row in 4-row tile), s=tid>>7 (group). Each thread: 64 channels of its group.
__global__ __launch_bounds__(256) void pasa_pool(
    const float* __restrict__ x, const float* __restrict__ sigma,
    float* __restrict__ out)
{
    int flat = blockIdx.x;                 // [0,512)
    int nf   = (flat & 7) * 64 + (flat >> 3);
    const int yq = nf & 31;
    const int n  = (nf >> 5) & 7;
    const int chh = nf >> 8;               // channel half: 0/1

    const int q = threadIdx.x & 31;
    const int r = (threadIdx.x >> 5) & 3;
    const int s = threadIdx.x >> 7;        // group 0/1

    const int y   = yq * 4 + r;
    const int px0 = q * 4;

    const int ym = (y == 0)      ? 1      : y - 1;
    const int yp = (y == HW - 1) ? HW - 2 : y + 1;
    const int lx = (px0 == 0)        ? 1      : px0 - 1;
    const int rx = (px0 + 4 > HW - 1)? HW - 2 : px0 + 4;

    // sigma for this quad & group: sgv[k][j], k = 3x3 tap, j = pixel-in-quad
    const float* sg = sigma + ((size_t)n * NOC + s * 9) * (HW * HW)
                            + (size_t)y * HW + px0;
    float sgv[9][4];
    #pragma unroll
    for (int k = 0; k < 9; ++k) {
        float4 t = *(const float4*)(sg + (size_t)k * HW * HW);
        sgv[k][0] = t.x; sgv[k][1] = t.y; sgv[k][2] = t.z; sgv[k][3] = t.w;
    }

    const int c0 = s * 128 + chh * 64;
    const float* xn = x + (size_t)n * NCH * HW * HW;
    float*       on = out + (size_t)n * NCH * HW * HW;

    for (int cc = 0; cc < 64; ++cc) {
        const int c = c0 + cc;
        const float* xc = xn + (size_t)c * (HW * HW);
        const float* rws[3] = { xc + (size_t)ym * HW, xc + (size_t)y * HW,
                                xc + (size_t)yp * HW };
        float ov[4] = {0.f, 0.f, 0.f, 0.f};
        #pragma unroll
        for (int dy = 0; dy < 3; ++dy) {
            const float* rr = rws[dy];
            float  w0 = rr[lx];
            float4 mm = *(const float4*)(rr + px0);
            float  w5 = rr[rx];
            float wv[6] = { w0, mm.x, mm.y, mm.z, mm.w, w5 };
            #pragma unroll
            for (int j = 0; j < 4; ++j) {
                #pragma unroll
                for (int dx = 0; dx < 3; ++dx)
                    ov[j] = fmaf(wv[j + dx], sgv[dy * 3 + dx][j], ov[j]);
            }
        }
        float4 o4 = { ov[0], ov[1], ov[2], ov[3] };
        *(float4*)(on + (size_t)c * (HW * HW) + (size_t)y * HW + px0) = o4;
    }
}

extern "C" void kernel_launch(void* const* d_in, const int* in_sizes, int n_in,
                              void* d_out, int out_size, void* d_ws, size_t ws_size,
                              hipStream_t stream) {
    const float* x     = (const float*)d_in[0];
    const float* w     = (const float*)d_in[1];
    const float* gamma = (const float*)d_in[2];
    const float* beta  = (const float*)d_in[3];
    const float* rmean = (const float*)d_in[4];
    const float* rvar  = (const float*)d_in[5];
    float* out   = (float*)d_out;
    float* sigma = (float*)d_ws;   // needs 8*18*128*128*4 = 9.44 MB

    pasa_conv_softmax<<<dim3(1024), dim3(128), 0, stream>>>(
        x, w, gamma, beta, rmean, rvar, sigma);
    pasa_pool<<<dim3(512), dim3(256), 0, stream>>>(x, sigma, out);
}

// Round 2
// 299.231 us; speedup vs baseline: 1.7506x; 1.7506x over previous
//
#include <hip/hip_runtime.h>
#include <cstdint>

#define HW  128
#define NCH 256
#define NOC 18      // G*K*K = 2*9
#define EPSBN 1e-5f
#define CHUNKS 4
#define ICPC (NCH / CHUNKS)   // 64 input channels per chunk
#define PLANE (HW * HW)       // 16384

// ---------------- Kernel W: transpose weights to [ic][oc][k] ---------------
// w[oc][ic][k] (18 x 256 x 9) -> wT[ic][oc][k] (256 x 162)
__global__ __launch_bounds__(256) void pasa_wt(
    const float* __restrict__ w, float* __restrict__ wT)
{
    int idx = blockIdx.x * 256 + threadIdx.x;      // 162*256 = 41472 exactly
    int k  = idx % 9;
    int t  = idx / 9;
    int ic = t % NCH;
    int oc = t / NCH;
    wT[ic * (NOC * 9) + oc * 9 + k] = w[idx];
}

// ---------------- Kernel A1: partial conv over one ic-chunk ----------------
// grid: CHUNKS*8*128 = 4096 blocks (chunk, n, y), 128 threads (pixel x)
// partial[((chunk*8+n)*NOC+oc)*PLANE + y*HW + px]
__global__ __launch_bounds__(128) void pasa_conv_part(
    const float* __restrict__ x, const float* __restrict__ wT,
    float* __restrict__ partial)
{
    int flat = blockIdx.x;                   // [0,4096)
    int nf   = (flat & 7) * 512 + (flat >> 3);   // XCD-contiguous
    const int chunk = nf >> 10;              // [0,4)
    const int n = (nf >> 7) & 7;             // [0,8)
    const int y = nf & 127;                  // [0,128)

    const int px = threadIdx.x;

    const int ym = (y == 0)      ? 1      : y - 1;
    const int yp = (y == HW - 1) ? HW - 2 : y + 1;
    const int xm = (px == 0)       ? 1      : px - 1;
    const int xq = (px == HW - 1)  ? HW - 2 : px + 1;

    const float* xn = x + (size_t)n * NCH * PLANE + (size_t)(chunk * ICPC) * PLANE;

    float acc[NOC];
    #pragma unroll
    for (int i = 0; i < NOC; ++i) acc[i] = 0.0f;

    const float* wt = wT + (size_t)(chunk * ICPC) * (NOC * 9);

    for (int ic = 0; ic < ICPC; ++ic) {
        const float* xc = xn + (size_t)ic * PLANE;
        const float* r0 = xc + ym * HW;
        const float* r1 = xc + y  * HW;
        const float* r2 = xc + yp * HW;
        float v[9];
        v[0] = r0[xm]; v[1] = r0[px]; v[2] = r0[xq];
        v[3] = r1[xm]; v[4] = r1[px]; v[5] = r1[xq];
        v[6] = r2[xm]; v[7] = r2[px]; v[8] = r2[xq];

        const float* wic = wt + ic * (NOC * 9);  // 162 contiguous dwords, uniform
        #pragma unroll
        for (int oc = 0; oc < NOC; ++oc) {
            #pragma unroll
            for (int k = 0; k < 9; ++k)
                acc[oc] = fmaf(v[k], wic[oc * 9 + k], acc[oc]);
        }
    }

    float* po = partial + ((size_t)(chunk * 8 + n) * NOC) * PLANE
                        + (size_t)y * HW + px;
    #pragma unroll
    for (int oc = 0; oc < NOC; ++oc)
        po[(size_t)oc * PLANE] = acc[oc];
}

// ---------------- Kernel A2: reduce chunks + BN + softmax ------------------
// grid: 1024 blocks (n, y), 128 threads (pixel x)
__global__ __launch_bounds__(128) void pasa_reduce_softmax(
    const float* __restrict__ partial,
    const float* __restrict__ gamma, const float* __restrict__ beta,
    const float* __restrict__ rmean, const float* __restrict__ rvar,
    float* __restrict__ sigma)
{
    int flat = blockIdx.x;                   // [0,1024)
    int nf   = (flat & 7) * 128 + (flat >> 3);
    const int n = nf >> 7;
    const int y = nf & 127;
    const int px = threadIdx.x;

    const size_t off = (size_t)y * HW + px;

    float vals[NOC];
    float m = -1e30f;
    #pragma unroll
    for (int oc = 0; oc < NOC; ++oc) {
        float s = 0.0f;
        #pragma unroll
        for (int ch = 0; ch < CHUNKS; ++ch)
            s += partial[((size_t)(ch * 8 + n) * NOC + oc) * PLANE + off];
        float sc = gamma[oc] * rsqrtf(rvar[oc] + EPSBN);
        float b  = beta[oc] - rmean[oc] * sc;
        float t  = fmaf(s, sc, b);
        vals[oc] = t;
        m = fmaxf(m, t);
    }
    float ssum = 0.0f;
    #pragma unroll
    for (int oc = 0; oc < NOC; ++oc) { vals[oc] = __expf(vals[oc] - m); ssum += vals[oc]; }
    const float inv = 1.0f / ssum;

    float* so = sigma + (size_t)n * NOC * PLANE + off;
    #pragma unroll
    for (int oc = 0; oc < NOC; ++oc)
        so[(size_t)oc * PLANE] = vals[oc] * inv;
}

// ---------------- Kernel B: per-pixel dynamic 3x3 pooling ------------------
__global__ __launch_bounds__(256) void pasa_pool(
    const float* __restrict__ x, const float* __restrict__ sigma,
    float* __restrict__ out)
{
    int flat = blockIdx.x;                 // [0,512)
    int nf   = (flat & 7) * 64 + (flat >> 3);
    const int yq = nf & 31;
    const int n  = (nf >> 5) & 7;
    const int chh = nf >> 8;               // channel half: 0/1

    const int q = threadIdx.x & 31;
    const int r = (threadIdx.x >> 5) & 3;
    const int s = threadIdx.x >> 7;        // group 0/1

    const int y   = yq * 4 + r;
    const int px0 = q * 4;

    const int ym = (y == 0)      ? 1      : y - 1;
    const int yp = (y == HW - 1) ? HW - 2 : y + 1;
    const int lx = (px0 == 0)        ? 1      : px0 - 1;
    const int rx = (px0 + 4 > HW - 1)? HW - 2 : px0 + 4;

    const float* sg = sigma + ((size_t)n * NOC + s * 9) * PLANE
                            + (size_t)y * HW + px0;
    float sgv[9][4];
    #pragma unroll
    for (int k = 0; k < 9; ++k) {
        float4 t = *(const float4*)(sg + (size_t)k * PLANE);
        sgv[k][0] = t.x; sgv[k][1] = t.y; sgv[k][2] = t.z; sgv[k][3] = t.w;
    }

    const int c0 = s * 128 + chh * 64;
    const float* xn = x + (size_t)n * NCH * PLANE;
    float*       on = out + (size_t)n * NCH * PLANE;

    for (int cc = 0; cc < 64; ++cc) {
        const int c = c0 + cc;
        const float* xc = xn + (size_t)c * PLANE;
        const float* rws[3] = { xc + (size_t)ym * HW, xc + (size_t)y * HW,
                                xc + (size_t)yp * HW };
        float ov[4] = {0.f, 0.f, 0.f, 0.f};
        #pragma unroll
        for (int dy = 0; dy < 3; ++dy) {
            const float* rr = rws[dy];
            float  w0 = rr[lx];
            float4 mm = *(const float4*)(rr + px0);
            float  w5 = rr[rx];
            float wv[6] = { w0, mm.x, mm.y, mm.z, mm.w, w5 };
            #pragma unroll
            for (int j = 0; j < 4; ++j) {
                #pragma unroll
                for (int dx = 0; dx < 3; ++dx)
                    ov[j] = fmaf(wv[j + dx], sgv[dy * 3 + dx][j], ov[j]);
            }
        }
        float4 o4 = { ov[0], ov[1], ov[2], ov[3] };
        *(float4*)(on + (size_t)c * PLANE + (size_t)y * HW + px0) = o4;
    }
}

extern "C" void kernel_launch(void* const* d_in, const int* in_sizes, int n_in,
                              void* d_out, int out_size, void* d_ws, size_t ws_size,
                              hipStream_t stream) {
    const float* x     = (const float*)d_in[0];
    const float* w     = (const float*)d_in[1];
    const float* gamma = (const float*)d_in[2];
    const float* beta  = (const float*)d_in[3];
    const float* rmean = (const float*)d_in[4];
    const float* rvar  = (const float*)d_in[5];
    float* out   = (float*)d_out;
    float* sigma = (float*)d_ws;                 // 8*18*16384*4 = 9.44 MB

    // scratch carved out of d_out (pool overwrites all of d_out last):
    //   partial: CHUNKS*8*18*16384 floats = 9.44M floats (37.7 MB) at offset 0
    //   wT:      41472 floats at float-offset 16M (64 MB)
    float* partial = out;
    float* wT      = out + (size_t)16 * 1024 * 1024;

    pasa_wt<<<dim3(162), dim3(256), 0, stream>>>(w, wT);
    pasa_conv_part<<<dim3(4096), dim3(128), 0, stream>>>(x, wT, partial);
    pasa_reduce_softmax<<<dim3(1024), dim3(128), 0, stream>>>(
        partial, gamma, beta, rmean, rvar, sigma);
    pasa_pool<<<dim3(512), dim3(256), 0, stream>>>(x, sigma, out);
}

// Round 4
// 156.655 us; speedup vs baseline: 3.3438x; 1.9101x over previous
//
#include <hip/hip_runtime.h>
#include <cstdint>

#define HW  128
#define NCH 256
#define NOC 18      // G*K*K
#define PLANE (HW * HW)
#define EPSBN 1e-5f

typedef __attribute__((ext_vector_type(8)))  short bf16x8;
typedef __attribute__((ext_vector_type(16))) float f32x16;

__device__ __forceinline__ unsigned short f2bf(float f) {
    union { float f; uint32_t u; } c; c.f = f;
    uint32_t u = c.u;
    uint32_t r = u + 0x7FFFu + ((u >> 16) & 1u);   // RNE
    return (unsigned short)(r >> 16);
}

// swizzled LDS byte offset for tile [slot(4)][px(130)][ic(64)] bf16
__device__ __forceinline__ int lds_off(int slot, int px, int ic) {
    int b = ((slot * 130 + px) * 64 + ic) * 2;
    return b ^ ((px & 7) << 4);
}

// ------------- Kernel W: pack weights -> wB[tap][ic>>3][oc(32 pad)][ic&7] bf16
__global__ __launch_bounds__(256) void pasa_wprep(
    const float* __restrict__ w, unsigned short* __restrict__ wB)
{
    int idx = blockIdx.x * 256 + threadIdx.x;      // 9*32*32*8 = 73728
    int icl = idx & 7;
    int oc  = (idx >> 3) & 31;
    int icb = (idx >> 8) & 31;
    int tap = idx >> 13;
    int ic  = icb * 8 + icl;
    float v = (oc < NOC) ? w[((size_t)oc * NCH + ic) * 9 + tap] : 0.0f;
    wB[idx] = f2bf(v);
}

// ------------- Kernel A: implicit-GEMM conv + BN + softmax (fused) ---------
// block: 512 thr = 8 waves; covers 2 output rows x 128 px. wave w:
// out_row=w>>2, px_tile=(w&3)*32. D = W·X : row(oc) from reg index,
// col(px)=lane&31, via mfma_f32_32x32x16_bf16(b=W, a=X, acc).
__global__ __launch_bounds__(512, 4) void pasa_conv_mfma(
    const float* __restrict__ x, const unsigned short* __restrict__ wB,
    const float* __restrict__ gamma, const float* __restrict__ beta,
    const float* __restrict__ rmean, const float* __restrict__ rvar,
    float* __restrict__ sigma)
{
    __shared__ __align__(16) char lds[4 * 130 * 64 * 2];   // 66560 B

    int flat = blockIdx.x;                 // [0,512)
    int nf   = (flat & 7) * 64 + (flat >> 3);  // XCD gets one image
    const int n  = nf >> 6;
    const int y0 = (nf & 63) * 2;

    const int tid  = threadIdx.x;
    const int lane = tid & 63;
    const int wv   = tid >> 6;             // wave 0..7
    const int m    = lane & 31;            // MFMA col (pixel in tile)
    const int hi   = lane >> 5;            // k-half selector

    // staged rows (reflect)
    const int team = tid >> 7;             // 0..3 -> LDS slot
    const int p128 = tid & 127;            // global px
    int grow;
    if      (team == 0) grow = (y0 == 0) ? 1 : y0 - 1;
    else if (team == 1) grow = y0;
    else if (team == 2) grow = y0 + 1;
    else                grow = (y0 + 1 == HW - 1) ? HW - 2 : y0 + 2;

    const float* xrow = x + (size_t)n * NCH * PLANE + (size_t)grow * HW;

    const int out_row = wv >> 2;
    const int px_tile = (wv & 3) * 32;

    f32x16 acc;
    #pragma unroll
    for (int i = 0; i < 16; ++i) acc[i] = 0.0f;

    for (int chunk = 0; chunk < 4; ++chunk) {
        const int icg0 = chunk * 64;
        // ---- stage 64 ic x 4 rows x 130 px (bf16, swizzled) ----
        #pragma unroll
        for (int it = 0; it < 8; ++it) {
            const int ic = icg0 + it * 8;
            float v[8];
            #pragma unroll
            for (int i = 0; i < 8; ++i)
                v[i] = xrow[(size_t)(ic + i) * PLANE + p128];
            int4 d;
            d.x = (uint32_t)f2bf(v[0]) | ((uint32_t)f2bf(v[1]) << 16);
            d.y = (uint32_t)f2bf(v[2]) | ((uint32_t)f2bf(v[3]) << 16);
            d.z = (uint32_t)f2bf(v[4]) | ((uint32_t)f2bf(v[5]) << 16);
            d.w = (uint32_t)f2bf(v[6]) | ((uint32_t)f2bf(v[7]) << 16);
            *(int4*)(lds + lds_off(team, p128 + 1, it * 8)) = d;
            if (p128 == 0) {               // left halo: reflect px=1
                float h[8];
                #pragma unroll
                for (int i = 0; i < 8; ++i)
                    h[i] = xrow[(size_t)(ic + i) * PLANE + 1];
                int4 e;
                e.x = (uint32_t)f2bf(h[0]) | ((uint32_t)f2bf(h[1]) << 16);
                e.y = (uint32_t)f2bf(h[2]) | ((uint32_t)f2bf(h[3]) << 16);
                e.z = (uint32_t)f2bf(h[4]) | ((uint32_t)f2bf(h[5]) << 16);
                e.w = (uint32_t)f2bf(h[6]) | ((uint32_t)f2bf(h[7]) << 16);
                *(int4*)(lds + lds_off(team, 0, it * 8)) = e;
            }
            if (p128 == 127) {             // right halo: reflect px=126
                float h[8];
                #pragma unroll
                for (int i = 0; i < 8; ++i)
                    h[i] = xrow[(size_t)(ic + i) * PLANE + 126];
                int4 e;
                e.x = (uint32_t)f2bf(h[0]) | ((uint32_t)f2bf(h[1]) << 16);
                e.y = (uint32_t)f2bf(h[2]) | ((uint32_t)f2bf(h[3]) << 16);
                e.z = (uint32_t)f2bf(h[4]) | ((uint32_t)f2bf(h[5]) << 16);
                e.w = (uint32_t)f2bf(h[6]) | ((uint32_t)f2bf(h[7]) << 16);
                *(int4*)(lds + lds_off(team, 129, it * 8)) = e;
            }
        }
        __syncthreads();
        // ---- MFMA: 9 taps x 4 k-steps, D = W·X ----
        #pragma unroll
        for (int tap = 0; tap < 9; ++tap) {
            const int dy = tap / 3;
            const int dx = tap % 3 - 1;
            const int slot = out_row + dy;
            const int apx  = px_tile + m + 1 + dx;
            #pragma unroll
            for (int ks = 0; ks < 4; ++ks) {
                const int k0 = ks * 16;
                bf16x8 a = *(const bf16x8*)(lds + lds_off(slot, apx, k0 + hi * 8));
                bf16x8 b = *(const bf16x8*)(wB +
                    (((size_t)tap * 32 + ((icg0 + k0) >> 3) + hi) * 32 + m) * 8);
                // A-operand = weights (row=oc), B-operand = patches (col=px)
                acc = __builtin_amdgcn_mfma_f32_32x32x16_bf16(b, a, acc, 0, 0, 0);
            }
        }
        __syncthreads();
    }

    // ---- epilogue: BN + softmax over 18 channels, write sigma ----
    // C/D layout: col(px)=lane&31, row(oc)=(r&3)+8*(r>>2)+4*hi
    float vals[16];
    float mx = -3.0e38f;
    #pragma unroll
    for (int r = 0; r < 16; ++r) {
        int oc = (r & 3) + 8 * (r >> 2) + 4 * hi;
        float v = -3.0e38f;
        if (oc < NOC) {
            float sc = gamma[oc] * rsqrtf(rvar[oc] + EPSBN);
            float b  = beta[oc] - rmean[oc] * sc;
            v = fmaf(acc[r], sc, b);
        }
        vals[r] = v;
        mx = fmaxf(mx, v);
    }
    mx = fmaxf(mx, __shfl_xor(mx, 32));
    float s = 0.0f;
    #pragma unroll
    for (int r = 0; r < 16; ++r) {
        int oc = (r & 3) + 8 * (r >> 2) + 4 * hi;
        float e = (oc < NOC) ? __expf(vals[r] - mx) : 0.0f;
        vals[r] = e;
        s += e;
    }
    s += __shfl_xor(s, 32);
    const float inv = 1.0f / s;

    float* so = sigma + (size_t)n * NOC * PLANE
              + (size_t)(y0 + out_row) * HW + px_tile + m;
    #pragma unroll
    for (int r = 0; r < 16; ++r) {
        int oc = (r & 3) + 8 * (r >> 2) + 4 * hi;
        if (oc < NOC) so[(size_t)oc * PLANE] = vals[r] * inv;
    }
}

// ------------- Kernel B: per-pixel dynamic 3x3 pooling ---------------------
__global__ __launch_bounds__(256) void pasa_pool(
    const float* __restrict__ x, const float* __restrict__ sigma,
    float* __restrict__ out)
{
    int flat = blockIdx.x;                 // [0,512)
    int nf   = (flat & 7) * 64 + (flat >> 3);
    const int yq = nf & 31;
    const int n  = (nf >> 5) & 7;
    const int chh = nf >> 8;               // channel half: 0/1

    const int q = threadIdx.x & 31;
    const int r = (threadIdx.x >> 5) & 3;
    const int s = threadIdx.x >> 7;        // group 0/1

    const int y   = yq * 4 + r;
    const int px0 = q * 4;

    const int ym = (y == 0)      ? 1      : y - 1;
    const int yp = (y == HW - 1) ? HW - 2 : y + 1;
    const int lx = (px0 == 0)        ? 1      : px0 - 1;
    const int rx = (px0 + 4 > HW - 1)? HW - 2 : px0 + 4;

    const float* sg = sigma + ((size_t)n * NOC + s * 9) * PLANE
                            + (size_t)y * HW + px0;
    float sgv[9][4];
    #pragma unroll
    for (int k = 0; k < 9; ++k) {
        float4 t = *(const float4*)(sg + (size_t)k * PLANE);
        sgv[k][0] = t.x; sgv[k][1] = t.y; sgv[k][2] = t.z; sgv[k][3] = t.w;
    }

    const int c0 = s * 128 + chh * 64;
    const float* xn = x + (size_t)n * NCH * PLANE;
    float*       on = out + (size_t)n * NCH * PLANE;

    for (int cc = 0; cc < 64; ++cc) {
        const int c = c0 + cc;
        const float* xc = xn + (size_t)c * PLANE;
        const float* rws[3] = { xc + (size_t)ym * HW, xc + (size_t)y * HW,
                                xc + (size_t)yp * HW };
        float ov[4] = {0.f, 0.f, 0.f, 0.f};
        #pragma unroll
        for (int dy = 0; dy < 3; ++dy) {
            const float* rr = rws[dy];
            float  w0 = rr[lx];
            float4 mm = *(const float4*)(rr + px0);
            float  w5 = rr[rx];
            float wvv[6] = { w0, mm.x, mm.y, mm.z, mm.w, w5 };
            #pragma unroll
            for (int j = 0; j < 4; ++j) {
                #pragma unroll
                for (int dx = 0; dx < 3; ++dx)
                    ov[j] = fmaf(wvv[j + dx], sgv[dy * 3 + dx][j], ov[j]);
            }
        }
        float4 o4 = { ov[0], ov[1], ov[2], ov[3] };
        *(float4*)(on + (size_t)c * PLANE + (size_t)y * HW + px0) = o4;
    }
}

extern "C" void kernel_launch(void* const* d_in, const int* in_sizes, int n_in,
                              void* d_out, int out_size, void* d_ws, size_t ws_size,
                              hipStream_t stream) {
    const float* x     = (const float*)d_in[0];
    const float* w     = (const float*)d_in[1];
    const float* gamma = (const float*)d_in[2];
    const float* beta  = (const float*)d_in[3];
    const float* rmean = (const float*)d_in[4];
    const float* rvar  = (const float*)d_in[5];
    float* out   = (float*)d_out;
    float* sigma = (float*)d_ws;                 // 8*18*16384*4 = 9.44 MB

    // wB scratch lives in d_out (pool fully overwrites d_out afterwards)
    unsigned short* wB = (unsigned short*)((char*)d_out + (size_t)64 * 1024 * 1024);

    pasa_wprep<<<dim3(288), dim3(256), 0, stream>>>(w, wB);
    pasa_conv_mfma<<<dim3(512), dim3(512), 0, stream>>>(
        x, wB, gamma, beta, rmean, rvar, sigma);
    pasa_pool<<<dim3(512), dim3(256), 0, stream>>>(x, sigma, out);
}

// Round 5
// 138.214 us; speedup vs baseline: 3.7899x; 1.1334x over previous
//
#include <hip/hip_runtime.h>
#include <cstdint>

#define HW  128
#define NCH 256
#define NOC 18      // G*K*K
#define PLANE (HW * HW)
#define EPSBN 1e-5f

typedef __attribute__((ext_vector_type(8)))  short bf16x8;
typedef __attribute__((ext_vector_type(16))) float f32x16;

__device__ __forceinline__ unsigned short f2bf(float f) {
    union { float f; uint32_t u; } c; c.f = f;
    uint32_t u = c.u;
    uint32_t r = u + 0x7FFFu + ((u >> 16) & 1u);   // RNE
    return (unsigned short)(r >> 16);
}

// swizzled LDS byte offset for tile [slot(4)][px(130)][ic(64)] bf16
__device__ __forceinline__ int lds_off(int slot, int px, int ic) {
    int b = ((slot * 130 + px) * 64 + ic) * 2;
    return b ^ ((px & 7) << 4);
}

// ------------- Kernel W: pack weights -> wB[tap][ic>>3][oc(32 pad)][ic&7] bf16
__global__ __launch_bounds__(256) void pasa_wprep(
    const float* __restrict__ w, unsigned short* __restrict__ wB)
{
    int idx = blockIdx.x * 256 + threadIdx.x;      // 9*32*32*8 = 73728
    int icl = idx & 7;
    int oc  = (idx >> 3) & 31;
    int icb = (idx >> 8) & 31;
    int tap = idx >> 13;
    int ic  = icb * 8 + icl;
    float v = (oc < NOC) ? w[((size_t)oc * NCH + ic) * 9 + tap] : 0.0f;
    wB[idx] = f2bf(v);
}

// ------------- Kernel A: implicit-GEMM conv + BN + softmax (fused) ---------
__global__ __launch_bounds__(512, 4) void pasa_conv_mfma(
    const float* __restrict__ x, const unsigned short* __restrict__ wB,
    const float* __restrict__ gamma, const float* __restrict__ beta,
    const float* __restrict__ rmean, const float* __restrict__ rvar,
    float* __restrict__ sigma)
{
    __shared__ __align__(16) char lds[4 * 130 * 64 * 2];   // 66560 B

    int flat = blockIdx.x;                 // [0,512)
    int nf   = (flat & 7) * 64 + (flat >> 3);  // XCD gets one image
    const int n  = nf >> 6;
    const int y0 = (nf & 63) * 2;

    const int tid  = threadIdx.x;
    const int lane = tid & 63;
    const int wv   = tid >> 6;             // wave 0..7
    const int m    = lane & 31;            // MFMA col (pixel in tile)
    const int hi   = lane >> 5;            // k-half selector

    const int team = tid >> 7;             // 0..3 -> LDS slot
    const int p128 = tid & 127;            // global px
    int grow;
    if      (team == 0) grow = (y0 == 0) ? 1 : y0 - 1;
    else if (team == 1) grow = y0;
    else if (team == 2) grow = y0 + 1;
    else                grow = (y0 + 1 == HW - 1) ? HW - 2 : y0 + 2;

    const float* xrow = x + (size_t)n * NCH * PLANE + (size_t)grow * HW;

    const int out_row = wv >> 2;
    const int px_tile = (wv & 3) * 32;

    f32x16 acc;
    #pragma unroll
    for (int i = 0; i < 16; ++i) acc[i] = 0.0f;

    for (int chunk = 0; chunk < 4; ++chunk) {
        const int icg0 = chunk * 64;
        #pragma unroll
        for (int it = 0; it < 8; ++it) {
            const int ic = icg0 + it * 8;
            float v[8];
            #pragma unroll
            for (int i = 0; i < 8; ++i)
                v[i] = xrow[(size_t)(ic + i) * PLANE + p128];
            int4 d;
            d.x = (uint32_t)f2bf(v[0]) | ((uint32_t)f2bf(v[1]) << 16);
            d.y = (uint32_t)f2bf(v[2]) | ((uint32_t)f2bf(v[3]) << 16);
            d.z = (uint32_t)f2bf(v[4]) | ((uint32_t)f2bf(v[5]) << 16);
            d.w = (uint32_t)f2bf(v[6]) | ((uint32_t)f2bf(v[7]) << 16);
            *(int4*)(lds + lds_off(team, p128 + 1, it * 8)) = d;
            if (p128 == 0) {               // left halo: reflect px=1
                float h[8];
                #pragma unroll
                for (int i = 0; i < 8; ++i)
                    h[i] = xrow[(size_t)(ic + i) * PLANE + 1];
                int4 e;
                e.x = (uint32_t)f2bf(h[0]) | ((uint32_t)f2bf(h[1]) << 16);
                e.y = (uint32_t)f2bf(h[2]) | ((uint32_t)f2bf(h[3]) << 16);
                e.z = (uint32_t)f2bf(h[4]) | ((uint32_t)f2bf(h[5]) << 16);
                e.w = (uint32_t)f2bf(h[6]) | ((uint32_t)f2bf(h[7]) << 16);
                *(int4*)(lds + lds_off(team, 0, it * 8)) = e;
            }
            if (p128 == 127) {             // right halo: reflect px=126
                float h[8];
                #pragma unroll
                for (int i = 0; i < 8; ++i)
                    h[i] = xrow[(size_t)(ic + i) * PLANE + 126];
                int4 e;
                e.x = (uint32_t)f2bf(h[0]) | ((uint32_t)f2bf(h[1]) << 16);
                e.y = (uint32_t)f2bf(h[2]) | ((uint32_t)f2bf(h[3]) << 16);
                e.z = (uint32_t)f2bf(h[4]) | ((uint32_t)f2bf(h[5]) << 16);
                e.w = (uint32_t)f2bf(h[6]) | ((uint32_t)f2bf(h[7]) << 16);
                *(int4*)(lds + lds_off(team, 129, it * 8)) = e;
            }
        }
        __syncthreads();
        #pragma unroll
        for (int tap = 0; tap < 9; ++tap) {
            const int dy = tap / 3;
            const int dx = tap % 3 - 1;
            const int slot = out_row + dy;
            const int apx  = px_tile + m + 1 + dx;
            #pragma unroll
            for (int ks = 0; ks < 4; ++ks) {
                const int k0 = ks * 16;
                bf16x8 a = *(const bf16x8*)(lds + lds_off(slot, apx, k0 + hi * 8));
                bf16x8 b = *(const bf16x8*)(wB +
                    (((size_t)tap * 32 + ((icg0 + k0) >> 3) + hi) * 32 + m) * 8);
                acc = __builtin_amdgcn_mfma_f32_32x32x16_bf16(b, a, acc, 0, 0, 0);
            }
        }
        __syncthreads();
    }

    // C/D layout: col(px)=lane&31, row(oc)=(r&3)+8*(r>>2)+4*hi
    float vals[16];
    float mx = -3.0e38f;
    #pragma unroll
    for (int r = 0; r < 16; ++r) {
        int oc = (r & 3) + 8 * (r >> 2) + 4 * hi;
        float v = -3.0e38f;
        if (oc < NOC) {
            float sc = gamma[oc] * rsqrtf(rvar[oc] + EPSBN);
            float b  = beta[oc] - rmean[oc] * sc;
            v = fmaf(acc[r], sc, b);
        }
        vals[r] = v;
        mx = fmaxf(mx, v);
    }
    mx = fmaxf(mx, __shfl_xor(mx, 32));
    float s = 0.0f;
    #pragma unroll
    for (int r = 0; r < 16; ++r) {
        int oc = (r & 3) + 8 * (r >> 2) + 4 * hi;
        float e = (oc < NOC) ? __expf(vals[r] - mx) : 0.0f;
        vals[r] = e;
        s += e;
    }
    s += __shfl_xor(s, 32);
    const float inv = 1.0f / s;

    float* so = sigma + (size_t)n * NOC * PLANE
              + (size_t)(y0 + out_row) * HW + px_tile + m;
    #pragma unroll
    for (int r = 0; r < 16; ++r) {
        int oc = (r & 3) + 8 * (r >> 2) + 4 * hi;
        if (oc < NOC) so[(size_t)oc * PLANE] = vals[r] * inv;
    }
}

// ------------- Kernel B: per-pixel dynamic 3x3 pooling ---------------------
// grid: 2048 blocks (n(8) x chsplit(8) x yq(32)); block 256 thr:
// q=tid&31 (pixel quad), r=(tid>>5)&3 (row in 4-row tile), s=tid>>7 (group).
// Each thread: 16 channels of its group -> 8 waves/SIMD occupancy.
__global__ __launch_bounds__(256) void pasa_pool(
    const float* __restrict__ x, const float* __restrict__ sigma,
    float* __restrict__ out)
{
    int flat = blockIdx.x;                 // [0,2048)
    int nf   = (flat & 7) * 256 + (flat >> 3);   // XCD owns one image
    const int n       = nf >> 8;
    const int chsplit = (nf >> 5) & 7;
    const int yq      = nf & 31;

    const int q = threadIdx.x & 31;
    const int r = (threadIdx.x >> 5) & 3;
    const int s = threadIdx.x >> 7;        // group 0/1

    const int y   = yq * 4 + r;
    const int px0 = q * 4;

    const int ym = (y == 0)      ? 1      : y - 1;
    const int yp = (y == HW - 1) ? HW - 2 : y + 1;
    const int lx = (px0 == 0)        ? 1      : px0 - 1;
    const int rx = (px0 + 4 > HW - 1)? HW - 2 : px0 + 4;

    const float* sg = sigma + ((size_t)n * NOC + s * 9) * PLANE
                            + (size_t)y * HW + px0;
    float sgv[9][4];
    #pragma unroll
    for (int k = 0; k < 9; ++k) {
        float4 t = *(const float4*)(sg + (size_t)k * PLANE);
        sgv[k][0] = t.x; sgv[k][1] = t.y; sgv[k][2] = t.z; sgv[k][3] = t.w;
    }

    const int c0 = s * 128 + chsplit * 16;
    const float* xn = x + (size_t)n * NCH * PLANE;
    float*       on = out + (size_t)n * NCH * PLANE;

    for (int cc = 0; cc < 16; ++cc) {
        const int c = c0 + cc;
        const float* xc = xn + (size_t)c * PLANE;
        const float* rws[3] = { xc + (size_t)ym * HW, xc + (size_t)y * HW,
                                xc + (size_t)yp * HW };
        float ov[4] = {0.f, 0.f, 0.f, 0.f};
        #pragma unroll
        for (int dy = 0; dy < 3; ++dy) {
            const float* rr = rws[dy];
            float  w0 = rr[lx];
            float4 mm = *(const float4*)(rr + px0);
            float  w5 = rr[rx];
            float wvv[6] = { w0, mm.x, mm.y, mm.z, mm.w, w5 };
            #pragma unroll
            for (int j = 0; j < 4; ++j) {
                #pragma unroll
                for (int dx = 0; dx < 3; ++dx)
                    ov[j] = fmaf(wvv[j + dx], sgv[dy * 3 + dx][j], ov[j]);
            }
        }
        float4 o4 = { ov[0], ov[1], ov[2], ov[3] };
        *(float4*)(on + (size_t)c * PLANE + (size_t)y * HW + px0) = o4;
    }
}

extern "C" void kernel_launch(void* const* d_in, const int* in_sizes, int n_in,
                              void* d_out, int out_size, void* d_ws, size_t ws_size,
                              hipStream_t stream) {
    const float* x     = (const float*)d_in[0];
    const float* w     = (const float*)d_in[1];
    const float* gamma = (const float*)d_in[2];
    const float* beta  = (const float*)d_in[3];
    const float* rmean = (const float*)d_in[4];
    const float* rvar  = (const float*)d_in[5];
    float* out   = (float*)d_out;
    float* sigma = (float*)d_ws;                 // 8*18*16384*4 = 9.44 MB

    unsigned short* wB = (unsigned short*)((char*)d_out + (size_t)64 * 1024 * 1024);

    pasa_wprep<<<dim3(288), dim3(256), 0, stream>>>(w, wB);
    pasa_conv_mfma<<<dim3(512), dim3(512), 0, stream>>>(
        x, wB, gamma, beta, rmean, rvar, sigma);
    pasa_pool<<<dim3(2048), dim3(256), 0, stream>>>(x, sigma, out);
}